// Round 23
// baseline (217.982 us; speedup 1.0000x reference)
//
#include <hip/hip_runtime.h>
#include <math.h>
#include <float.h>

#define NFEAT 300
#define HID 32
#define NCLS 10
#define GP 16     // padded row stride (bf16) for layer-2 logits
#define BSZ 128   // nodes per dst-bucket (bucket = dst >> 7)
#define TILE 8192 // edges per k_part tile
#define WT_S 328  // Wt row stride (bf16): 656 B, 16B-aligned
#define XR_S 40   // xs row stride (bf16): 80 B, 16B-aligned

typedef unsigned int uint;

__device__ __forceinline__ unsigned short f2bf(float f) {  // RNE float->bf16
    uint u = __float_as_uint(f);
    u += 0x7FFFu + ((u >> 16) & 1u);
    return (unsigned short)(u >> 16);
}
__device__ __forceinline__ uint pack2(float a, float b) {
    return (uint)f2bf(a) | ((uint)f2bf(b) << 16);
}
// accumulate 8 bf16 (uint4) into 8 f32
__device__ __forceinline__ void acc8(float* a, uint4 v) {
    a[0] += __uint_as_float(v.x << 16);
    a[1] += __uint_as_float(v.x & 0xFFFF0000u);
    a[2] += __uint_as_float(v.y << 16);
    a[3] += __uint_as_float(v.y & 0xFFFF0000u);
    a[4] += __uint_as_float(v.z << 16);
    a[5] += __uint_as_float(v.z & 0xFFFF0000u);
    a[6] += __uint_as_float(v.w << 16);
    a[7] += __uint_as_float(v.w & 0xFFFF0000u);
}
__device__ __forceinline__ void set8(float* a, uint4 v) {
    a[0] = __uint_as_float(v.x << 16);
    a[1] = __uint_as_float(v.x & 0xFFFF0000u);
    a[2] = __uint_as_float(v.y << 16);
    a[3] = __uint_as_float(v.y & 0xFFFF0000u);
    a[4] = __uint_as_float(v.z << 16);
    a[5] = __uint_as_float(v.z & 0xFFFF0000u);
    a[6] = __uint_as_float(v.w << 16);
    a[7] = __uint_as_float(v.w & 0xFFFF0000u);
}

__global__ void k_zero_i(int* __restrict__ p, int n) {
    int i = blockIdx.x * 256 + threadIdx.x;
    if (i < n) p[i] = 0;
}

// bucket-level histogram: LDS-privatized, merged via global atomics (782 counters)
__global__ __launch_bounds__(256) void k_bhist(const int* __restrict__ ei, int E, int NB,
                                               int* __restrict__ bcnt) {
    __shared__ int h[1024];
    for (int i = threadIdx.x; i < NB; i += 256) h[i] = 0;
    __syncthreads();
    for (long long i = (long long)blockIdx.x * 256 + threadIdx.x; i < E;
         i += (long long)gridDim.x * 256)
        atomicAdd(&h[ei[E + i] >> 7], 1);
    __syncthreads();
    for (int i = threadIdx.x; i < NB; i += 256) {
        int v = h[i];
        if (v) atomicAdd(&bcnt[i], v);
    }
}

// single-block exclusive scan of bucket counts -> bases (and bcur seed)
__global__ void k_bscan(const int* __restrict__ bcnt, int NB, int E,
                        int* __restrict__ bases, int* __restrict__ bcur) {
    __shared__ int s[1024];
    int tid = threadIdx.x;
    int v = (tid < NB) ? bcnt[tid] : 0;
    s[tid] = v;
    __syncthreads();
    for (int off = 1; off < 1024; off <<= 1) {
        int t = (tid >= off) ? s[tid - off] : 0;
        __syncthreads();
        s[tid] += t;
        __syncthreads();
    }
    if (tid < NB) {
        int ex = s[tid] - v;
        bases[tid] = ex;
        bcur[tid] = ex;
        if (tid == NB - 1) bases[NB] = E;
    }
}

// partition edges into dst-buckets; output packed (dst_local<<17 | src), bucket-contiguous
__global__ __launch_bounds__(256) void k_part(const int* __restrict__ ei, int E, int NB,
                                              int* __restrict__ bcur, int* __restrict__ pp) {
    __shared__ int hist[1024], lbase[1024], gbase[1024], lcur[1024];
    __shared__ int stage[TILE], tgt[TILE];
    int* part = gbase;  // alias: gbase unused until after scan
    int tid = threadIdx.x;
    long long t0 = (long long)blockIdx.x * TILE;
    int nE = (int)(((long long)E - t0 < TILE) ? ((long long)E - t0) : TILE);

    for (int b = tid; b < NB; b += 256) hist[b] = 0;
    __syncthreads();
    for (int i = tid; i < nE; i += 256) {
        int d = ei[E + t0 + i];
        atomicAdd(&hist[d >> 7], 1);
    }
    __syncthreads();
    int i0 = tid * 4;
    int c0 = (i0 + 0 < NB) ? hist[i0 + 0] : 0;
    int c1 = (i0 + 1 < NB) ? hist[i0 + 1] : 0;
    int c2 = (i0 + 2 < NB) ? hist[i0 + 2] : 0;
    int c3 = (i0 + 3 < NB) ? hist[i0 + 3] : 0;
    int sum = c0 + c1 + c2 + c3;
    part[tid] = sum;
    __syncthreads();
    for (int off = 1; off < 256; off <<= 1) {
        int t = (tid >= off) ? part[tid - off] : 0;
        __syncthreads();
        part[tid] += t;
        __syncthreads();
    }
    int ex = part[tid] - sum;
    if (i0 + 0 < NB) { lbase[i0 + 0] = ex; ex += c0; }
    if (i0 + 1 < NB) { lbase[i0 + 1] = ex; ex += c1; }
    if (i0 + 2 < NB) { lbase[i0 + 2] = ex; ex += c2; }
    if (i0 + 3 < NB) { lbase[i0 + 3] = ex; ex += c3; }
    __syncthreads();
    for (int b = tid; b < NB; b += 256) {
        int h = hist[b];
        gbase[b] = h ? atomicAdd(&bcur[b], h) : 0;
        lcur[b] = 0;
    }
    __syncthreads();
    for (int i = tid; i < nE; i += 256) {
        int s = ei[t0 + i];
        int d = ei[E + t0 + i];
        int b = d >> 7;
        int lo = atomicAdd(&lcur[b], 1);
        int slot = lbase[b] + lo;
        stage[slot] = ((d - (b << 7)) << 17) | s;
        tgt[slot] = gbase[b] + lo;
    }
    __syncthreads();
    for (int i = tid; i < nE; i += 256)
        pp[tgt[i]] = stage[i];
}

// per-bucket: count node degrees from pp, scan -> rowptr/dinv, then scatter col
__global__ __launch_bounds__(256) void k_csr(const int* __restrict__ pp,
                                             const int* __restrict__ bases,
                                             int N, int E,
                                             int* __restrict__ rowptr,
                                             float* __restrict__ dinv,
                                             int* __restrict__ col) {
    __shared__ int lc[BSZ], rp[BSZ], sc[BSZ];
    int b = blockIdx.x, tid = threadIdx.x;
    int n0 = b << 7;
    int base = bases[b];
    int cnt = bases[b + 1] - base;
    if (tid < BSZ) lc[tid] = 0;
    __syncthreads();
    for (int i = tid; i < cnt; i += 256)
        atomicAdd(&lc[pp[base + i] >> 17], 1);
    __syncthreads();
    if (tid < BSZ) sc[tid] = lc[tid];
    __syncthreads();
    for (int off = 1; off < BSZ; off <<= 1) {
        int t = (tid < BSZ && tid >= off) ? sc[tid - off] : 0;
        __syncthreads();
        if (tid < BSZ) sc[tid] += t;
        __syncthreads();
    }
    if (tid < BSZ) {
        int node = n0 + tid;
        int ex = base + sc[tid] - lc[tid];
        rp[tid] = ex;
        if (node < N) {
            rowptr[node] = ex;
            dinv[node] = rsqrtf((float)(lc[tid] + 1));
            if (node == N - 1) rowptr[N] = E;
        }
        lc[tid] = 0;
    }
    __syncthreads();
    for (int i = tid; i < cnt; i += 256) {
        int v = pp[base + i];
        int dl = v >> 17;
        int lo = atomicAdd(&lc[dl], 1);
        col[rp[dl] + lo] = v & 0x1FFFF;
    }
}

// h1s[n][k] = bf16( dinv[n] * (x @ W1)[n][k] ) via MFMA 16x16x32 bf16.
// Block = 256 nodes, 4 waves; wave owns 64 nodes = 4 node-16-tiles x 2 out-halves.
// Wt = W1^T bf16 in LDS (zero-padded k>=300); x chunks (32 feats) bf16-staged,
// double-buffered, reg-staged pipeline (write -> barrier -> issue next -> MFMA).
__global__ __launch_bounds__(256) void k_gemm1(const float* __restrict__ x,
                                               const float* __restrict__ W1,
                                               const float* __restrict__ dinv,
                                               uint* __restrict__ h1s, int n) {
    typedef __attribute__((ext_vector_type(8))) short bf16x8;
    typedef __attribute__((ext_vector_type(4))) float f32x4;
    __shared__ unsigned short Wt[32 * WT_S];       // 20.5 KB
    __shared__ unsigned short xs[2][256 * XR_S];   // 2 x 20 KB
    const int tid = threadIdx.x;
    const int lane = tid & 63;
    const int w = tid >> 6;
    const int n0 = blockIdx.x * 256;
    const float4* x4 = reinterpret_cast<const float4*>(x);
    unsigned short* h1u = reinterpret_cast<unsigned short*>(h1s);

    // issue chunk-0 x loads (stay in flight during Wt staging)
    float4 u[8];
#pragma unroll
    for (int m = 0; m < 8; ++m) {
        int idx = m * 256 + tid, node = idx >> 3, f = idx & 7;
        u[m] = x4[(size_t)min(n0 + node, n - 1) * 75 + f];
    }
    // stage Wt = W1^T in bf16; zero-pad k = 300..319
    {
        const float4* w4 = reinterpret_cast<const float4*>(W1);
        for (int idx = tid; idx < 2400; idx += 256) {  // 300*32/4 float4s
            float4 v = w4[idx];
            int j = idx >> 3, o = (idx & 7) * 4;
            Wt[(o + 0) * WT_S + j] = f2bf(v.x);
            Wt[(o + 1) * WT_S + j] = f2bf(v.y);
            Wt[(o + 2) * WT_S + j] = f2bf(v.z);
            Wt[(o + 3) * WT_S + j] = f2bf(v.w);
        }
        for (int i = tid; i < 32 * 20; i += 256) {     // pad cols 300..319
            int o = i / 20, j = 300 + i % 20;
            Wt[o * WT_S + j] = 0;
        }
    }

    f32x4 acc[4][2];
#pragma unroll
    for (int t = 0; t < 4; ++t)
#pragma unroll
        for (int h = 0; h < 2; ++h) acc[t][h] = (f32x4){0.f, 0.f, 0.f, 0.f};

    const int kb = (lane >> 4) << 3;  // k base within chunk
    const int cl = lane & 15;
    int cur = 0;
    for (int ch = 0; ch < 10; ++ch) {
        // WRITE staged regs into xs[cur] as bf16 (vmcnt waits here)
        if (ch < 9) {
#pragma unroll
            for (int m = 0; m < 8; ++m) {
                int idx = m * 256 + tid, node = idx >> 3, f = idx & 7;
                uint2 pk;
                pk.x = pack2(u[m].x, u[m].y);
                pk.y = pack2(u[m].z, u[m].w);
                *reinterpret_cast<uint2*>(&xs[cur][node * XR_S + f * 4]) = pk;
            }
        } else {  // tail: 12 feats data + zero-pad cols 12..31
#pragma unroll
            for (int m = 0; m < 3; ++m) {
                int idx = m * 256 + tid, node = idx / 3, f = idx % 3;
                uint2 pk;
                pk.x = pack2(u[m].x, u[m].y);
                pk.y = pack2(u[m].z, u[m].w);
                *reinterpret_cast<uint2*>(&xs[cur][node * XR_S + f * 4]) = pk;
            }
            uint2 z; z.x = 0u; z.y = 0u;
#pragma unroll
            for (int m = 0; m < 5; ++m) {
                int idx = m * 256 + tid, node = idx / 5, slot = 3 + idx % 5;
                *reinterpret_cast<uint2*>(&xs[cur][node * XR_S + slot * 4]) = z;
            }
        }
        __syncthreads();
        // ISSUE next chunk's loads (overlap with MFMA compute)
        if (ch + 1 < 9) {
#pragma unroll
            for (int m = 0; m < 8; ++m) {
                int idx = m * 256 + tid, node = idx >> 3, f = idx & 7;
                u[m] = x4[(size_t)min(n0 + node, n - 1) * 75 + (ch + 1) * 8 + f];
            }
        } else if (ch + 1 == 9) {
#pragma unroll
            for (int m = 0; m < 3; ++m) {
                int idx = m * 256 + tid, node = idx / 3, f = idx % 3;
                u[m] = x4[(size_t)min(n0 + node, n - 1) * 75 + 72 + f];
            }
        }
        // COMPUTE: 2 B-frags + 4 A-frags -> 8 MFMAs
        const unsigned short* xb = xs[cur];
        bf16x8 b0 = *reinterpret_cast<const bf16x8*>(&Wt[cl * WT_S + ch * 32 + kb]);
        bf16x8 b1 = *reinterpret_cast<const bf16x8*>(&Wt[(cl + 16) * WT_S + ch * 32 + kb]);
#pragma unroll
        for (int t = 0; t < 4; ++t) {
            bf16x8 a = *reinterpret_cast<const bf16x8*>(
                &xb[(w * 64 + t * 16 + cl) * XR_S + kb]);
            acc[t][0] = __builtin_amdgcn_mfma_f32_16x16x32_bf16(a, b0, acc[t][0], 0, 0, 0);
            acc[t][1] = __builtin_amdgcn_mfma_f32_16x16x32_bf16(a, b1, acc[t][1], 0, 0, 0);
        }
        cur ^= 1;
    }
    // epilogue: D[node][out], node=(lane>>4)*4+reg within tile, out=lane&15 (+16)
    const int rq = (lane >> 4) * 4;
#pragma unroll
    for (int t = 0; t < 4; ++t) {
        int nb = n0 + w * 64 + t * 16 + rq;
        float4 dv = *reinterpret_cast<const float4*>(&dinv[nb]);
        float dr[4] = {dv.x, dv.y, dv.z, dv.w};
#pragma unroll
        for (int r = 0; r < 4; ++r) {
            int node = nb + r;
            if (node < n) {
                h1u[(size_t)node * 32 + cl]      = f2bf(dr[r] * acc[t][0][r]);
                h1u[(size_t)node * 32 + 16 + cl] = f2bf(dr[r] * acc[t][1][r]);
            }
        }
    }
}

// CSR gather aggregate layer 1 (bf16 h1s rows, 64 B/node), fused bias + tanh.
// 4 lanes/node x uint4 (8 bf16 = 16 B); 4-edge unroll -> 4 KB in flight/wave.
__global__ __launch_bounds__(256) void k_agg1(const uint4* __restrict__ h1s,
                                              const int* __restrict__ rowptr,
                                              const int* __restrict__ col,
                                              const float* __restrict__ dinv,
                                              const float* __restrict__ b1,
                                              float* __restrict__ h2, int n) {
    int node = blockIdx.x * 64 + (threadIdx.x >> 2);
    int l = threadIdx.x & 3;  // uint4 lane within node (k = 8l..8l+7)
    if (node >= n) return;
    int beg = rowptr[node], end = rowptr[node + 1];
    float a0[8], a1[8], a2[8], a3[8];
    set8(a0, h1s[(size_t)node * 4 + l]);  // self-loop term
#pragma unroll
    for (int i = 0; i < 8; ++i) { a1[i] = 0.f; a2[i] = 0.f; a3[i] = 0.f; }
    int j = beg;
    for (; j + 3 < end; j += 4) {
        int s0 = col[j], s1 = col[j + 1], s2 = col[j + 2], s3 = col[j + 3];
        uint4 u0 = h1s[(size_t)s0 * 4 + l];
        uint4 u1 = h1s[(size_t)s1 * 4 + l];
        uint4 u2 = h1s[(size_t)s2 * 4 + l];
        uint4 u3 = h1s[(size_t)s3 * 4 + l];
        acc8(a0, u0); acc8(a1, u1); acc8(a2, u2); acc8(a3, u3);
    }
    for (; j < end; ++j) acc8(a0, h1s[(size_t)col[j] * 4 + l]);
    float dd = dinv[node];
    float4 bv0 = reinterpret_cast<const float4*>(b1)[2 * l];
    float4 bv1 = reinterpret_cast<const float4*>(b1)[2 * l + 1];
    float bb[8] = {bv0.x, bv0.y, bv0.z, bv0.w, bv1.x, bv1.y, bv1.z, bv1.w};
    float r[8];
#pragma unroll
    for (int i = 0; i < 8; ++i)
        r[i] = tanhf(fmaf(dd, (a0[i] + a1[i]) + (a2[i] + a3[i]), bb[i]));
    float4* dst = reinterpret_cast<float4*>(h2 + (size_t)node * HID + 8 * l);
    dst[0] = make_float4(r[0], r[1], r[2], r[3]);
    dst[1] = make_float4(r[4], r[5], r[6], r[7]);
}

// gs[n][c] = bf16( dinv[n] * sum_k h2[n][k] * W2[k][c] ), row stride GP=16 bf16
__global__ __launch_bounds__(256) void k_gemm2(const float* __restrict__ h2,
                                               const float* __restrict__ W2,
                                               const float* __restrict__ dinv,
                                               unsigned short* __restrict__ gs, int n) {
    __shared__ float Ws[HID * NCLS];
    for (int i = threadIdx.x; i < HID * NCLS; i += 256) Ws[i] = W2[i];
    __syncthreads();
    int t = blockIdx.x * 256 + threadIdx.x;
    int node = t >> 4, c = t & 15;
    if (node >= n || c >= NCLS) return;
    const float* hr = h2 + (size_t)node * HID;
    float acc = 0.f;
#pragma unroll
    for (int k = 0; k < HID; ++k) acc = fmaf(hr[k], Ws[k * NCLS + c], acc);
    gs[(size_t)node * GP + c] = f2bf(acc * dinv[node]);
}

// CSR gather aggregate layer 2 (bf16 gs rows, 32 B/node), fused bias + log-softmax.
// 2 lanes/node x uint4 (8 bf16 = classes 8l..8l+7); 4-edge unroll.
__global__ __launch_bounds__(256) void k_agg2(const uint4* __restrict__ gs,
                                              const int* __restrict__ rowptr,
                                              const int* __restrict__ col,
                                              const float* __restrict__ dinv,
                                              const float* __restrict__ b2,
                                              float* __restrict__ out, int n) {
    int node = blockIdx.x * 128 + (threadIdx.x >> 1);
    int l = threadIdx.x & 1;  // uint4 lane: classes 8l..8l+7
    if (node >= n) return;
    int beg = rowptr[node], end = rowptr[node + 1];
    float a0[8], a1[8], a2[8], a3[8];
    set8(a0, gs[(size_t)node * 2 + l]);  // self-loop term
#pragma unroll
    for (int i = 0; i < 8; ++i) { a1[i] = 0.f; a2[i] = 0.f; a3[i] = 0.f; }
    int j = beg;
    for (; j + 3 < end; j += 4) {
        int s0 = col[j], s1 = col[j + 1], s2 = col[j + 2], s3 = col[j + 3];
        uint4 u0 = gs[(size_t)s0 * 2 + l];
        uint4 u1 = gs[(size_t)s1 * 2 + l];
        uint4 u2 = gs[(size_t)s2 * 2 + l];
        uint4 u3 = gs[(size_t)s3 * 2 + l];
        acc8(a0, u0); acc8(a1, u1); acc8(a2, u2); acc8(a3, u3);
    }
    for (; j < end; ++j) acc8(a0, gs[(size_t)col[j] * 2 + l]);
    float dd = dinv[node];
    int c0 = 8 * l;
    float val[8];
#pragma unroll
    for (int i = 0; i < 8; ++i) {
        int c = c0 + i;
        val[i] = (c < NCLS)
            ? fmaf(dd, (a0[i] + a1[i]) + (a2[i] + a3[i]), b2[c])
            : -FLT_MAX;
    }
    float m = val[0];
#pragma unroll
    for (int i = 1; i < 8; ++i) m = fmaxf(m, val[i]);
    m = fmaxf(m, __shfl_xor(m, 1, 2));
    float s = 0.f;
#pragma unroll
    for (int i = 0; i < 8; ++i)
        if (c0 + i < NCLS) s += expf(val[i] - m);
    s += __shfl_xor(s, 1, 2);
    float ls = m + logf(s);
    float* orow = out + (size_t)node * NCLS;
#pragma unroll
    for (int i = 0; i < 8; ++i)
        if (c0 + i < NCLS) orow[c0 + i] = val[i] - ls;
}

static inline size_t align256(size_t b) { return (b + 255) & ~(size_t)255; }

extern "C" void kernel_launch(void* const* d_in, const int* in_sizes, int n_in,
                              void* d_out, int out_size, void* d_ws, size_t ws_size,
                              hipStream_t stream) {
    const float* x  = (const float*)d_in[0];
    const int*   ei = (const int*)d_in[1];
    const float* W1 = (const float*)d_in[2];
    const float* b1 = (const float*)d_in[3];
    const float* W2 = (const float*)d_in[4];
    const float* b2 = (const float*)d_in[5];
    float* out = (float*)d_out;

    const int N = in_sizes[0] / NFEAT;   // 100000
    const int E = in_sizes[1] / 2;       // 3200000
    const int NB = (N + BSZ - 1) / BSZ;  // 782 dst-buckets

    char* p = (char*)d_ws;
    int* bcnt   = (int*)p;  p += align256(1024 * 4);
    int* bases  = (int*)p;  p += align256(1025 * 4);
    int* bcur   = (int*)p;  p += align256(1024 * 4);
    int* rowptr = (int*)p;  p += align256((size_t)(N + 1) * 4);
    int* pp     = (int*)p;  p += align256((size_t)E * 4);
    int* col    = (int*)p;  p += align256((size_t)E * 4);
    float* dinv = (float*)p; p += align256((size_t)N * 4);
    uint* h1s   = (uint*)p;  p += align256((size_t)N * HID * 2);  // bf16
    float* h2   = (float*)p; p += align256((size_t)N * HID * 4);  // f32
    unsigned short* gsb = (unsigned short*)h1s;  // bf16, N*GP*2 <= h1s size

    dim3 B(256);
    int nT = (E + TILE - 1) / TILE;

    k_zero_i<<<4, B, 0, stream>>>(bcnt, 1024);
    k_bhist<<<128, B, 0, stream>>>(ei, E, NB, bcnt);
    k_bscan<<<1, 1024, 0, stream>>>(bcnt, NB, E, bases, bcur);
    k_part<<<nT, B, 0, stream>>>(ei, E, NB, bcur, pp);
    k_csr<<<NB, B, 0, stream>>>(pp, bases, N, E, rowptr, dinv, col);

    k_gemm1<<<(N + 255) / 256, B, 0, stream>>>(x, W1, dinv, h1s, N);
    k_agg1<<<(N + 63) / 64, B, 0, stream>>>((const uint4*)h1s, rowptr, col, dinv, b1, h2, N);
    k_gemm2<<<(N * 16 + 255) / 256, B, 0, stream>>>(h2, W2, dinv, gsb, N);
    k_agg2<<<(N + 127) / 128, B, 0, stream>>>((const uint4*)gsb, rowptr, col, dinv, b2, out, N);
}